// Round 6
// baseline (307.216 us; speedup 1.0000x reference)
//
#include <hip/hip_runtime.h>
#include <stdint.h>

// Problem constants
#define K_CODES 8192
#define D 256
#define NROWS 16384      // 16 * 32 * 32
#define NELEM 4194304    // 16 * 256 * 32 * 32

// ws layout (bytes)
#define WS_ENORM   0x00000u                 // 8192 f32 = 32 KB
#define WS_KEYS    0x08000u                 // 16384 u64 = 128 KB
#define WS_ICOUNTS 0x28000u                 // 8192 i32 = 32 KB
#define WS_CURSOR  0x30000u                 // 8192 i32 = 32 KB
#define WS_BASE    0x38000u                 // 8192 i32 = 32 KB
#define WS_ROWLIST 0x40000u                 // 16384 i32 = 64 KB
#define WS_PART    0x50000u                 // 256 f32
#define WS_XHI     0x60000u                 // 16384*256 bf16 = 8 MB
#define WS_XLO     (WS_XHI + 0x800000u)     // 8 MB
#define WS_EHI     (WS_XLO + 0x800000u)     // 4 MB
#define WS_ELO     (WS_EHI + 0x400000u)     // 4 MB

// out offsets (floats), concatenated return order
#define O_QST  0
#define O_LOSS 4194304
#define O_PERP 4194305
#define O_EMB  4194306
#define O_CS   6291458
#define O_EAVG 6299650

typedef unsigned short u16;
typedef __attribute__((ext_vector_type(8))) short bf16x8;
typedef __attribute__((ext_vector_type(4))) float f32x4;

// bf16 round-to-nearest-even split helpers
__device__ __forceinline__ u16 f2bf(float f) {
    uint32_t u = __float_as_uint(f);
    u += 0x7FFFu + ((u >> 16) & 1u);
    return (u16)(u >> 16);
}
__device__ __forceinline__ float bf2f(u16 h) {
    return __uint_as_float(((uint32_t)h) << 16);
}

__device__ __forceinline__ void glds16(const u16* g, u16* lds_base) {
    __builtin_amdgcn_global_load_lds(
        (const __attribute__((address_space(1))) uint32_t*)g,
        (__attribute__((address_space(3))) uint32_t*)lds_base, 16, 0, 0);
}

// ---------------------------------------------------------------------------
// Split emb rows into bf16 hi/lo planes (same [k][c] layout) + row norms.
__global__ __launch_bounds__(256) void prep_emb_kernel(const float* __restrict__ emb,
                                                       u16* __restrict__ eh,
                                                       u16* __restrict__ el,
                                                       float* __restrict__ enorm) {
    const int k = blockIdx.x, t = threadIdx.x;
    const size_t i = (size_t)k * D + t;
    const float v = emb[i];
    const u16 h = f2bf(v);
    const float r = v - bf2f(h);  // exact
    eh[i] = h;
    el[i] = f2bf(r);
    float s = v * v;
#pragma unroll
    for (int off = 32; off; off >>= 1) s += __shfl_down(s, off, 64);
    __shared__ float sm[4];
    if ((t & 63) == 0) sm[t >> 6] = s;
    __syncthreads();
    if (t == 0) enorm[k] = sm[0] + sm[1] + sm[2] + sm[3];
}

// ---------------------------------------------------------------------------
// Split + transpose x: [b][c][hw] f32 -> xhi/xlo [n = b*1024+hw][c] bf16.
__global__ __launch_bounds__(256) void prep_x_kernel(const float* __restrict__ x,
                                                     u16* __restrict__ xhi,
                                                     u16* __restrict__ xlo) {
    __shared__ u16 Lh[64][72];
    __shared__ u16 Ll[64][72];
    const int hw0 = blockIdx.x << 6;
    const int c0 = blockIdx.y << 6;
    const int b = blockIdx.z;
    const int t = threadIdx.x, l = t & 63, w = t >> 6;
#pragma unroll
    for (int i = 0; i < 16; ++i) {
        const int cl = w * 16 + i;
        const float v = x[(((size_t)(b * 256 + c0 + cl)) << 10) + hw0 + l];
        const u16 h = f2bf(v);
        Lh[l][cl] = h;
        Ll[l][cl] = f2bf(v - bf2f(h));
    }
    __syncthreads();
    const int r = t >> 2, cs = t & 3;
    const size_t n = (((size_t)b) << 10) + hw0 + r;
    const size_t o = n * D + c0 + cs * 16;
    *(uint4*)&xhi[o]     = *(const uint4*)&Lh[r][cs * 16];
    *(uint4*)&xhi[o + 8] = *(const uint4*)&Lh[r][cs * 16 + 8];
    *(uint4*)&xlo[o]     = *(const uint4*)&Ll[r][cs * 16];
    *(uint4*)&xlo[o + 8] = *(const uint4*)&Ll[r][cs * 16 + 8];
}

// ---------------------------------------------------------------------------
// Distance GEMM via bf16 hi/lo-split MFMA + fused argmin.
// A-resident LDS (128 KB, XOR-swizzled) + B double-buffer (2x16 KB) +
// register pipeline. NEW in R6:
//   (1) ALL A-hi fragments (ct-invariant) preloaded into 128 VGPRs once ->
//       per-kt LDS reads drop 16->12 per wave (pipe time 578 cyc < MFMA 931).
//   (2) sched_group_barrier interleave 4x[1 VMEM-rd, 3 DS-rd, 12 MFMA]:
//       at 1 wave/SIMD issue is in-order; segregated read->MFMA sections ADD
//       (R5: 46% MfmaUtil). Interleaving hides LDS issue under MFMA shadow.
#define BM 128
#define BN 128
#define SLICES 2
#define CT_PER 32

__global__ __launch_bounds__(256, 1) void dist_kernel(const u16* __restrict__ xhi,
                                                      const u16* __restrict__ xlo,
                                                      const u16* __restrict__ ehi,
                                                      const u16* __restrict__ elo,
                                                      const float* __restrict__ enorm,
                                                      unsigned long long* __restrict__ keys) {
    extern __shared__ __align__(16) u16 lds[];   // [0,32768)=Ah [32768,65536)=Al [65536,81920)=B dbuf (u16 idx)

    const int tid = threadIdx.x;
    const int l = tid & 63, w = tid >> 6;
    const int wr = w >> 1, wc = w & 1;       // wave's 64x64 quadrant
    const int slice = blockIdx.x;            // 0..1
    const int n0 = blockIdx.y * BM;          // row block
    const int md = l & 15, quad = l >> 4;

    // ---- stage A once: window win (1KB) covers rows 2win..2win+1 ----------
#pragma unroll
    for (int wd = 0; wd < 16; ++wd) {
        const int win = w * 16 + wd;
        const int rA = 2 * win + (l >> 5);
        const int g = (l & 31) ^ (rA & 31);
        const size_t src = (size_t)(n0 + rA) * D + g * 8;
        glds16(xhi + src, &lds[win * 512]);
        glds16(xlo + src, &lds[32768 + win * 512]);
    }

    // ---- B staging per-lane source base ------------------------------------
    const int rloc = l >> 3, sB = l & 7, gB = sB ^ rloc;
    const u16* PB[4];
#pragma unroll
    for (int w8 = 0; w8 < 4; ++w8) {
        const u16* pl = (gB & 4) ? elo : ehi;
        PB[w8] = pl + (size_t)(slice * 4096 + w * 32 + w8 * 8 + rloc) * D + (gB & 3) * 8;
    }
    const int bdst = 65536 + (w * 32) * 64;  // wave-uniform LDS dest (u16 idx)

    // stage B(m=0) into buf 0
#pragma unroll
    for (int w8 = 0; w8 < 4; ++w8) glds16(PB[w8], &lds[bdst + w8 * 512]);

    // ---- frag-read address constants --------------------------------------
    int rbase[4], rh[4];                     // A frags: row rA = wr*64+i*16+md
#pragma unroll
    for (int i = 0; i < 4; ++i) {
        const int rA = wr * 64 + i * 16 + md;
        rbase[i] = rA * 256;
        rh[i] = rA & 31;
    }
    int offBH[4], offBL[4];                  // B frags: code cr = wc*64+j*16+md
#pragma unroll
    for (int j = 0; j < 4; ++j) {
        const int cr = wc * 64 + j * 16 + md;
        offBH[j] = 65536 + cr * 64 + ((quad) ^ (md & 7)) * 8;
        offBL[j] = 65536 + cr * 64 + ((quad + 4) ^ (md & 7)) * 8;
    }

    // ---- prologue: wait for A + B(0), preload ALL A-hi frags to registers --
    __syncthreads();
    bf16x8 fahk[8][4];                       // 128 VGPRs, ct-invariant
#pragma unroll
    for (int kt = 0; kt < 8; ++kt)
#pragma unroll
        for (int i = 0; i < 4; ++i) {
            const int slot = ((kt << 2) | quad) ^ rh[i];
            fahk[kt][i] = *(const bf16x8*)&lds[rbase[i] + slot * 8];
        }

    float rbv[4][4];
    int rbi[4][4];
#pragma unroll
    for (int i = 0; i < 4; ++i)
#pragma unroll
        for (int r = 0; r < 4; ++r) { rbv[i][r] = 1e30f; rbi[i][r] = 0; }

    f32x4 acc[4][4];
#pragma unroll
    for (int i = 0; i < 4; ++i)
#pragma unroll
        for (int j = 0; j < 4; ++j) acc[i][j] = (f32x4)0.f;

    bf16x8 fal[2][4], fbh[2][4], fbl[2][4];  // pipelined frag sets (A-lo, B)

    // prefetch enorm for ct=0
    float ecr[4];
#pragma unroll
    for (int j = 0; j < 4; ++j) ecr[j] = enorm[slice * 4096 + wc * 64 + j * 16 + md];

    for (int ct = 0; ct < CT_PER; ++ct) {
#pragma unroll
        for (int kt = 0; kt < 8; ++kt) {
            __syncthreads();   // drains stage(m) [vmcnt] + F(m-1) reads [lgkm]
            // ---- stage B(m+1) into buf (m+1)&1 ----
            if (kt < 7) {
                const int soff = ct * 32768 + (kt + 1) * 32;
                const int db = bdst + (((kt + 1) & 1) << 13);
#pragma unroll
                for (int w8 = 0; w8 < 4; ++w8) glds16(PB[w8] + soff, &lds[db + w8 * 512]);
            } else if (ct < CT_PER - 1) {
                const int soff = (ct + 1) * 32768;
#pragma unroll
                for (int w8 = 0; w8 < 4; ++w8) glds16(PB[w8] + soff, &lds[bdst + w8 * 512]);
            }
            // ---- issue frag reads F(m) into set p = kt&1 (A-lo + B only) ----
            const int p = kt & 1, bufo = p << 13;
#pragma unroll
            for (int i = 0; i < 4; ++i) {
                const int slot = ((kt << 2) | quad) ^ rh[i];
                fal[p][i] = *(const bf16x8*)&lds[32768 + rbase[i] + slot * 8];
            }
#pragma unroll
            for (int j = 0; j < 4; ++j) {
                fbh[p][j] = *(const bf16x8*)&lds[bufo + offBH[j]];
                fbl[p][j] = *(const bf16x8*)&lds[bufo + offBL[j]];
            }
            // ---- compute MFMA(m-1) from set q = p^1, A-hi from fahk --------
            if (kt > 0 || ct > 0) {
                const int q = p ^ 1;
                const int kq = (kt + 7) & 7;   // kt of body m-1
#pragma unroll
                for (int i = 0; i < 4; ++i)
#pragma unroll
                    for (int j = 0; j < 4; ++j) {
                        acc[i][j] = __builtin_amdgcn_mfma_f32_16x16x32_bf16(fahk[kq][i], fbh[q][j], acc[i][j], 0, 0, 0);
                        acc[i][j] = __builtin_amdgcn_mfma_f32_16x16x32_bf16(fahk[kq][i], fbl[q][j], acc[i][j], 0, 0, 0);
                        acc[i][j] = __builtin_amdgcn_mfma_f32_16x16x32_bf16(fal[q][i],  fbh[q][j], acc[i][j], 0, 0, 0);
                    }
                if (kt == 0) {
                    // MFMA above completed ct-1 -> merge, reload ecr, zero acc
                    const int gc0 = slice * 4096 + (ct - 1) * 128;
#pragma unroll
                    for (int i = 0; i < 4; ++i)
#pragma unroll
                        for (int r = 0; r < 4; ++r)
#pragma unroll
                            for (int j = 0; j < 4; ++j) {
                                const float s = fmaf(-2.f, acc[i][j][r], ecr[j]);
                                const int ci = gc0 + wc * 64 + j * 16 + md;
                                if (s < rbv[i][r]) { rbv[i][r] = s; rbi[i][r] = ci; }
                            }
#pragma unroll
                    for (int j = 0; j < 4; ++j)
                        ecr[j] = enorm[slice * 4096 + ct * 128 + wc * 64 + j * 16 + md];
#pragma unroll
                    for (int i = 0; i < 4; ++i)
#pragma unroll
                        for (int j = 0; j < 4; ++j) acc[i][j] = (f32x4)0.f;
                }
            }
            // ---- scheduler: interleave stage/ds-read/MFMA (AITER-style) ----
#pragma unroll
            for (int g = 0; g < 4; ++g) {
                __builtin_amdgcn_sched_group_barrier(0x020, 1, 0);  // 1 VMEM read (stage)
                __builtin_amdgcn_sched_group_barrier(0x100, 3, 0);  // 3 DS reads
                __builtin_amdgcn_sched_group_barrier(0x008, 12, 0); // 12 MFMA
            }
        }
    }

    // ---- drain: MFMA(255) from set 1 (kt=7), merge ct=31 ------------------
    {
#pragma unroll
        for (int i = 0; i < 4; ++i)
#pragma unroll
            for (int j = 0; j < 4; ++j) {
                acc[i][j] = __builtin_amdgcn_mfma_f32_16x16x32_bf16(fahk[7][i], fbh[1][j], acc[i][j], 0, 0, 0);
                acc[i][j] = __builtin_amdgcn_mfma_f32_16x16x32_bf16(fahk[7][i], fbl[1][j], acc[i][j], 0, 0, 0);
                acc[i][j] = __builtin_amdgcn_mfma_f32_16x16x32_bf16(fal[1][i],  fbh[1][j], acc[i][j], 0, 0, 0);
            }
        const int gc0 = slice * 4096 + (CT_PER - 1) * 128;
#pragma unroll
        for (int i = 0; i < 4; ++i)
#pragma unroll
            for (int r = 0; r < 4; ++r)
#pragma unroll
                for (int j = 0; j < 4; ++j) {
                    const float s = fmaf(-2.f, acc[i][j][r], ecr[j]);
                    const int ci = gc0 + wc * 64 + j * 16 + md;
                    if (s < rbv[i][r]) { rbv[i][r] = s; rbi[i][r] = ci; }
                }
    }

    // Epilogue (once per block): reduce across md lanes, atomicMin global key.
#pragma unroll
    for (int i = 0; i < 4; ++i)
#pragma unroll
        for (int r = 0; r < 4; ++r) {
            float bv = rbv[i][r];
            int bi = rbi[i][r];
#pragma unroll
            for (int m = 1; m < 16; m <<= 1) {
                const float ov = __shfl_xor(bv, m, 64);
                const int oi = __shfl_xor(bi, m, 64);
                if (ov < bv || (ov == bv && oi < bi)) { bv = ov; bi = oi; }
            }
            if (md == 0) {
                unsigned int u = __float_as_uint(bv);
                u = (u & 0x80000000u) ? ~u : (u | 0x80000000u);
                const unsigned long long key = ((unsigned long long)u << 32) | (unsigned int)bi;
                atomicMin(&keys[n0 + wr * 64 + i * 16 + quad * 4 + r], key);
            }
        }
}

// ---------------------------------------------------------------------------
// quantized_st + loss partials + integer code counts
__global__ __launch_bounds__(256) void quant_loss_kernel(const float* __restrict__ x,
                                                         const float* __restrict__ emb,
                                                         const unsigned long long* __restrict__ keys,
                                                         float* __restrict__ out,
                                                         float* __restrict__ partials,
                                                         int* __restrict__ icounts) {
    const int blk = blockIdx.x;
    const int b = blk >> 4;
    const int hw0 = (blk & 15) << 6;
    const int l = threadIdx.x & 63;
    const int cq = threadIdx.x >> 6;
    const int hw = hw0 + l;
    const int n = (b << 10) + hw;
    const int code = (int)(keys[n] & 0xFFFFFFFFull);
    if (threadIdx.x < 64) atomicAdd(&icounts[code], 1);
    const float* erow = emb + (size_t)code * D;
    const float* xb = x + (((size_t)b * 256) << 10) + hw;
    float* ob = out + O_QST + (((size_t)b * 256) << 10) + hw;
    float lsum = 0.f;
#pragma unroll 4
    for (int c = cq; c < D; c += 4) {
        const float xv = xb[(size_t)c << 10];
        const float ev = erow[c];
        ob[(size_t)c << 10] = xv + (ev - xv);
        const float d = xv - ev;
        lsum = fmaf(d, d, lsum);
    }
    __shared__ float sm[4];
    const int lane = threadIdx.x & 63, wv = threadIdx.x >> 6;
#pragma unroll
    for (int off = 32; off; off >>= 1) lsum += __shfl_down(lsum, off, 64);
    if (lane == 0) sm[wv] = lsum;
    __syncthreads();
    if (threadIdx.x == 0) partials[blockIdx.x] = sm[0] + sm[1] + sm[2] + sm[3];
}

// ---------------------------------------------------------------------------
// Exclusive scan of icounts -> basearr; also final loss + perplexity scalars.
__global__ __launch_bounds__(256) void scan_final_kernel(const int* __restrict__ icounts,
                                                         int* __restrict__ basearr,
                                                         const float* __restrict__ partials,
                                                         float* __restrict__ out) {
    const int t = threadIdx.x, lane = t & 63, w = t >> 6;
    int loc = 0;
    float ps = 0.f;
    for (int i = 0; i < 32; ++i) {
        const int c = icounts[t * 32 + i];
        loc += c;
        const float p = (float)c * (1.0f / 16384.0f);
        ps += p * logf(p + 1e-10f);
    }
    // inclusive scan of loc within wave
    int v = loc;
#pragma unroll
    for (int off = 1; off < 64; off <<= 1) {
        const int u = __shfl_up(v, off, 64);
        if (lane >= off) v += u;
    }
    __shared__ int wsum[4];
    __shared__ float fs[8];
    if (lane == 63) wsum[w] = v;
    // reduce loss + perplexity partials
    float lp = partials[t];
#pragma unroll
    for (int off = 32; off; off >>= 1) {
        lp += __shfl_down(lp, off, 64);
        ps += __shfl_down(ps, off, 64);
    }
    if (lane == 0) { fs[w] = lp; fs[4 + w] = ps; }
    __syncthreads();
    int pre = 0;
    for (int i = 0; i < w; ++i) pre += wsum[i];
    int b = pre + v - loc;  // exclusive base for this thread's 32 bins
    for (int i = 0; i < 32; ++i) {
        basearr[t * 32 + i] = b;
        b += icounts[t * 32 + i];
    }
    if (t == 0) {
        out[O_LOSS] = 0.25f * ((fs[0] + fs[1] + fs[2] + fs[3]) / 4194304.0f);
        out[O_PERP] = expf(-(fs[4] + fs[5] + fs[6] + fs[7]));
    }
}

// ---------------------------------------------------------------------------
// Counting-sort slot assignment: rowlist[base[code] + pos] = n
__global__ __launch_bounds__(256) void slot_kernel(const unsigned long long* __restrict__ keys,
                                                   const int* __restrict__ basearr,
                                                   int* __restrict__ cursor,
                                                   int* __restrict__ rowlist) {
    const int n = blockIdx.x * 256 + threadIdx.x;
    const int code = (int)(keys[n] & 0xFFFFFFFFull);
    const int pos = atomicAdd(&cursor[code], 1);
    rowlist[basearr[code] + pos] = n;
}

// ---------------------------------------------------------------------------
// Per-code gather-sum of x rows (replaces atomic scatter) fused with EMA.
__global__ __launch_bounds__(256) void gather_ema_kernel(const u16* __restrict__ xhi,
                                                         const u16* __restrict__ xlo,
                                                         const int* __restrict__ icounts,
                                                         const int* __restrict__ basearr,
                                                         const int* __restrict__ rowlist,
                                                         const float* __restrict__ embed_avg,
                                                         const float* __restrict__ cluster_size,
                                                         float* __restrict__ out) {
    const int k = blockIdx.x, c = threadIdx.x;
    const int cnt = icounts[k], b0 = basearr[k];
    float s = 0.f;
    for (int t = 0; t < cnt; ++t) {
        const int n = rowlist[b0 + t];  // wave-uniform
        s += bf2f(xhi[(size_t)n * D + c]) + bf2f(xlo[(size_t)n * D + c]);
    }
    const float ncs = cluster_size[k] * 0.99f + 0.01f * (float)cnt;
    const size_t i = (size_t)k * D + c;
    const float na = embed_avg[i] * 0.99f + 0.01f * s;
    out[O_EAVG + i] = na;
    out[O_EMB + i] = na / fmaxf(ncs, 1e-5f);
    if (c == 0) out[O_CS + k] = ncs;
}

// ---------------------------------------------------------------------------
extern "C" void kernel_launch(void* const* d_in, const int* in_sizes, int n_in,
                              void* d_out, int out_size, void* d_ws, size_t ws_size,
                              hipStream_t stream) {
    const float* x            = (const float*)d_in[0];
    const float* emb          = (const float*)d_in[1];
    const float* cluster_size = (const float*)d_in[2];
    const float* embed_avg    = (const float*)d_in[3];
    float* out = (float*)d_out;
    char* ws = (char*)d_ws;

    float* enorm = (float*)(ws + WS_ENORM);
    unsigned long long* keys = (unsigned long long*)(ws + WS_KEYS);
    int* icounts = (int*)(ws + WS_ICOUNTS);
    int* cursor = (int*)(ws + WS_CURSOR);
    int* basearr = (int*)(ws + WS_BASE);
    int* rowlist = (int*)(ws + WS_ROWLIST);
    float* partials = (float*)(ws + WS_PART);
    u16* xhi = (u16*)(ws + WS_XHI);
    u16* xlo = (u16*)(ws + WS_XLO);
    u16* ehi = (u16*)(ws + WS_EHI);
    u16* elo = (u16*)(ws + WS_ELO);

    static int lds_attr_set = 0;
    if (!lds_attr_set) {
        hipFuncSetAttribute((const void*)dist_kernel,
                            hipFuncAttributeMaxDynamicSharedMemorySize, 163840);
        lds_attr_set = 1;
    }

    hipMemsetAsync(ws + WS_ICOUNTS, 0, 0x10000, stream);           // icounts+cursor
    hipMemsetAsync(ws + WS_KEYS, 0xFF, NROWS * 8, stream);         // argmin keys

    prep_emb_kernel<<<K_CODES, 256, 0, stream>>>(emb, ehi, elo, enorm);
    prep_x_kernel<<<dim3(16, 4, 16), 256, 0, stream>>>(x, xhi, xlo);
    dist_kernel<<<dim3(SLICES, NROWS / BM), 256, 163840, stream>>>(xhi, xlo, ehi, elo, enorm, keys);
    quant_loss_kernel<<<256, 256, 0, stream>>>(x, emb, keys, out, partials, icounts);
    scan_final_kernel<<<1, 256, 0, stream>>>(icounts, basearr, partials, out);
    slot_kernel<<<NROWS / 256, 256, 0, stream>>>(keys, basearr, cursor, rowlist);
    gather_ema_kernel<<<K_CODES, 256, 0, stream>>>(xhi, xlo, icounts, basearr, rowlist,
                                                   embed_avg, cluster_size, out);
}

// Round 7
// 293.594 us; speedup vs baseline: 1.0464x; 1.0464x over previous
//
#include <hip/hip_runtime.h>
#include <stdint.h>

// Problem constants
#define K_CODES 8192
#define D 256
#define NROWS 16384      // 16 * 32 * 32
#define NELEM 4194304    // 16 * 256 * 32 * 32

// ws layout (bytes)
#define WS_ENORM   0x00000u                 // 8192 f32 = 32 KB
#define WS_KEYS    0x08000u                 // 16384 u64 = 128 KB
#define WS_ICOUNTS 0x28000u                 // 8192 i32 = 32 KB
#define WS_CURSOR  0x30000u                 // 8192 i32 = 32 KB
#define WS_BASE    0x38000u                 // 8192 i32 = 32 KB
#define WS_ROWLIST 0x40000u                 // 16384 i32 = 64 KB
#define WS_PART    0x50000u                 // 256 f32
#define WS_XHI     0x60000u                 // 16384*256 bf16 = 8 MB
#define WS_XLO     (WS_XHI + 0x800000u)     // 8 MB
#define WS_EHI     (WS_XLO + 0x800000u)     // 4 MB
#define WS_ELO     (WS_EHI + 0x400000u)     // 4 MB

// out offsets (floats), concatenated return order
#define O_QST  0
#define O_LOSS 4194304
#define O_PERP 4194305
#define O_EMB  4194306
#define O_CS   6291458
#define O_EAVG 6299650

typedef unsigned short u16;
typedef __attribute__((ext_vector_type(8))) short bf16x8;
typedef __attribute__((ext_vector_type(4))) float f32x4;

// bf16 round-to-nearest-even split helpers
__device__ __forceinline__ u16 f2bf(float f) {
    uint32_t u = __float_as_uint(f);
    u += 0x7FFFu + ((u >> 16) & 1u);
    return (u16)(u >> 16);
}
__device__ __forceinline__ float bf2f(u16 h) {
    return __uint_as_float(((uint32_t)h) << 16);
}

__device__ __forceinline__ void glds16(const u16* g, u16* lds_base) {
    __builtin_amdgcn_global_load_lds(
        (const __attribute__((address_space(1))) uint32_t*)g,
        (__attribute__((address_space(3))) uint32_t*)lds_base, 16, 0, 0);
}

// ---------------------------------------------------------------------------
// Fused prep: emb hi/lo split + norms (blocks 0..8191), x split+transpose
// (blocks 8192..9215), buffer init: keys=~0, icounts=cursor=0 (blocks 9216..).
__global__ __launch_bounds__(256) void prep_kernel(const float* __restrict__ emb,
                                                   const float* __restrict__ x,
                                                   u16* __restrict__ eh,
                                                   u16* __restrict__ el,
                                                   float* __restrict__ enorm,
                                                   u16* __restrict__ xhi,
                                                   u16* __restrict__ xlo,
                                                   unsigned long long* __restrict__ keys,
                                                   int* __restrict__ icounts,
                                                   int* __restrict__ cursor) {
    __shared__ u16 Lh[64][72];
    __shared__ u16 Ll[64][72];
    const int bid = blockIdx.x, t = threadIdx.x;
    if (bid < 8192) {
        // ---- emb split + norm ----
        const int k = bid;
        const size_t i = (size_t)k * D + t;
        const float v = emb[i];
        const u16 h = f2bf(v);
        eh[i] = h;
        el[i] = f2bf(v - bf2f(h));
        float s = v * v;
#pragma unroll
        for (int off = 32; off; off >>= 1) s += __shfl_down(s, off, 64);
        __shared__ float sm[4];
        if ((t & 63) == 0) sm[t >> 6] = s;
        __syncthreads();
        if (t == 0) enorm[k] = sm[0] + sm[1] + sm[2] + sm[3];
    } else if (bid < 9216) {
        // ---- x split + transpose: [b][c][hw] f32 -> [n][c] bf16 hi/lo ----
        const int px = bid - 8192;
        const int hw0 = (px & 15) << 6;
        const int c0 = ((px >> 4) & 3) << 6;
        const int b = px >> 6;
        const int l = t & 63, w = t >> 6;
#pragma unroll
        for (int i = 0; i < 16; ++i) {
            const int cl = w * 16 + i;
            const float v = x[(((size_t)(b * 256 + c0 + cl)) << 10) + hw0 + l];
            const u16 h = f2bf(v);
            Lh[l][cl] = h;
            Ll[l][cl] = f2bf(v - bf2f(h));
        }
        __syncthreads();
        const int r = t >> 2, cs = t & 3;
        const size_t n = (((size_t)b) << 10) + hw0 + r;
        const size_t o = n * D + c0 + cs * 16;
        *(uint4*)&xhi[o]     = *(const uint4*)&Lh[r][cs * 16];
        *(uint4*)&xhi[o + 8] = *(const uint4*)&Lh[r][cs * 16 + 8];
        *(uint4*)&xlo[o]     = *(const uint4*)&Ll[r][cs * 16];
        *(uint4*)&xlo[o + 8] = *(const uint4*)&Ll[r][cs * 16 + 8];
    } else {
        // ---- init ----
        const int n = (bid - 9216) * 256 + t;
        keys[n] = ~0ull;
        if (n < K_CODES) { icounts[n] = 0; cursor[n] = 0; }
    }
}

// ---------------------------------------------------------------------------
// Distance GEMM via bf16 hi/lo-split MFMA + fused argmin.
// BARRIER-FREE K-loop (AITER-style): the per-kt __syncthreads rendezvous was
// the structural ~2x stall (R4-R6 plateau at 44-47% MfmaUtil). Design:
//   - A-hi block-resident in LDS [0,64K), staged once, XOR-swizzled.
//   - A-lo in PERSISTENT REGISTERS (128 VGPR/wave), preloaded via the LDS
//     region that B buffers later overlay (2 prologue barriers only).
//   - B: wave-PRIVATE double buffers (4 waves x 2 x 8 KB = 64 KB) -> no
//     inter-wave coupling. Per body m: stage B(m+1) -> s_waitcnt vmcnt(0)
//     (stage(m), issued a full body earlier, has landed -> zero stall) ->
//     frag reads F(m) -> MFMA(m-1) from reg set (m-1)&1. All remaining
//     hazards are register deps (compiler-tracked) or disjoint LDS bufs.
#define BM 128
#define BN 128
#define SLICES 2
#define CT_PER 32

__global__ __launch_bounds__(256, 1) void dist_kernel(const u16* __restrict__ xhi,
                                                      const u16* __restrict__ xlo,
                                                      const u16* __restrict__ ehi,
                                                      const u16* __restrict__ elo,
                                                      const float* __restrict__ enorm,
                                                      unsigned long long* __restrict__ keys) {
    extern __shared__ __align__(16) u16 lds[];  // u16 idx: Ahi [0,32768); [32768,65536) = A-lo staging then wave-private B dbufs

    const int tid = threadIdx.x;
    const int l = tid & 63, w = tid >> 6;
    const int wr = w >> 1, wc = w & 1;       // wave's 64x64 quadrant
    const int slice = blockIdx.x;            // 0..1
    const int n0 = blockIdx.y * BM;          // row block
    const int md = l & 15, quad = l >> 4;

    // ---- stage A-hi -> [0,32768), A-lo -> [32768,65536) (temp) -----------
#pragma unroll
    for (int wd = 0; wd < 16; ++wd) {
        const int win = w * 16 + wd;         // 1 KB window = rows 2win,2win+1
        const int rA = 2 * win + (l >> 5);
        const int g = (l & 31) ^ (rA & 31);
        const size_t src = (size_t)(n0 + rA) * D + g * 8;
        glds16(xhi + src, &lds[win * 512]);
        glds16(xlo + src, &lds[32768 + win * 512]);
    }

    // frag addr constants
    int rbase[4], rh[4];
#pragma unroll
    for (int i = 0; i < 4; ++i) {
        const int rA = wr * 64 + i * 16 + md;
        rbase[i] = rA * 256;
        rh[i] = rA & 31;
    }

    __syncthreads();                         // A hi+lo staged (vmcnt drained)

    // ---- A-lo -> persistent registers (wave reads its own 64 rows) -------
    bf16x8 falo[8][4];                       // 128 VGPR, ct-invariant
#pragma unroll
    for (int kt = 0; kt < 8; ++kt)
#pragma unroll
        for (int i = 0; i < 4; ++i) {
            const int slot = ((kt << 2) | quad) ^ rh[i];
            falo[kt][i] = *(const bf16x8*)&lds[32768 + rbase[i] + slot * 8];
        }

    __syncthreads();                         // all waves done: B may overlay

    // ---- wave-private B staging setup -------------------------------------
    const int WB = 32768 + w * 8192;         // this wave's dbuf (2 x 4096 u16)
    const int rloc = l >> 3, sB = l & 7, gB = sB ^ rloc;
    const u16* PB[8];
#pragma unroll
    for (int c8 = 0; c8 < 8; ++c8) {
        const u16* pl = (gB & 4) ? elo : ehi;
        PB[c8] = pl + (size_t)(slice * 4096 + wc * 64 + c8 * 8 + rloc) * D + (gB & 3) * 8;
    }
    // stage B(m=0) into buf 0
#pragma unroll
    for (int c8 = 0; c8 < 8; ++c8) glds16(PB[c8], &lds[WB + c8 * 512]);

    int offBH[4], offBL[4];                  // local code cloc = j*16+md
#pragma unroll
    for (int j = 0; j < 4; ++j) {
        const int cloc = j * 16 + md;
        offBH[j] = WB + cloc * 64 + ((quad) ^ (md & 7)) * 8;
        offBL[j] = WB + cloc * 64 + ((quad + 4) ^ (md & 7)) * 8;
    }

    float rbv[4][4];
    int rbi[4][4];
#pragma unroll
    for (int i = 0; i < 4; ++i)
#pragma unroll
        for (int r = 0; r < 4; ++r) { rbv[i][r] = 1e30f; rbi[i][r] = 0; }

    f32x4 acc[4][4];
#pragma unroll
    for (int i = 0; i < 4; ++i)
#pragma unroll
        for (int j = 0; j < 4; ++j) acc[i][j] = (f32x4)0.f;

    bf16x8 fahi[2][4], fbh[2][4], fbl[2][4]; // pipelined frag sets

    // prefetch enorm for ct=0
    float ecr[4];
#pragma unroll
    for (int j = 0; j < 4; ++j) ecr[j] = enorm[slice * 4096 + wc * 64 + j * 16 + md];

    for (int ct = 0; ct < CT_PER; ++ct) {
#pragma unroll
        for (int kt = 0; kt < 8; ++kt) {
            // stage(m) (issued one full body ago) must be in LDS before F(m)
            __builtin_amdgcn_s_waitcnt(0x0F70);   // vmcnt(0), lgkm/exp free
            __builtin_amdgcn_sched_barrier(0);    // pin reads below the wait
            const int m = ct * 8 + kt;
            // ---- stage B(m+1) into buf (m+1)&1 (disjoint from F(m)'s buf) --
            if (m < CT_PER * 8 - 1) {
                const int m1 = m + 1;
                const int soff = (m1 >> 3) * 32768 + (m1 & 7) * 32;
                const int db = WB + ((m1 & 1) << 12);
#pragma unroll
                for (int c8 = 0; c8 < 8; ++c8) glds16(PB[c8] + soff, &lds[db + c8 * 512]);
            }
            // ---- frag reads F(m) into set p = m&1 = kt&1 ----
            const int p = kt & 1, bufo = p << 12;
#pragma unroll
            for (int i = 0; i < 4; ++i) {
                const int slot = ((kt << 2) | quad) ^ rh[i];
                fahi[p][i] = *(const bf16x8*)&lds[rbase[i] + slot * 8];
            }
#pragma unroll
            for (int j = 0; j < 4; ++j) {
                fbh[p][j] = *(const bf16x8*)&lds[bufo + offBH[j]];
                fbl[p][j] = *(const bf16x8*)&lds[bufo + offBL[j]];
            }
            // ---- compute MFMA(m-1): set q, A-lo from persistent regs ------
            if (kt > 0 || ct > 0) {
                const int q = p ^ 1;
                const int kq = (kt + 7) & 7;   // kt index of body m-1
#pragma unroll
                for (int i = 0; i < 4; ++i)
#pragma unroll
                    for (int j = 0; j < 4; ++j) {
                        acc[i][j] = __builtin_amdgcn_mfma_f32_16x16x32_bf16(fahi[q][i], fbh[q][j], acc[i][j], 0, 0, 0);
                        acc[i][j] = __builtin_amdgcn_mfma_f32_16x16x32_bf16(fahi[q][i], fbl[q][j], acc[i][j], 0, 0, 0);
                        acc[i][j] = __builtin_amdgcn_mfma_f32_16x16x32_bf16(falo[kq][i], fbh[q][j], acc[i][j], 0, 0, 0);
                    }
                if (kt == 0) {
                    // MFMA above completed ct-1 -> merge, reload ecr, zero acc
                    const int gc0 = slice * 4096 + (ct - 1) * 128;
#pragma unroll
                    for (int i = 0; i < 4; ++i)
#pragma unroll
                        for (int r = 0; r < 4; ++r)
#pragma unroll
                            for (int j = 0; j < 4; ++j) {
                                const float s = fmaf(-2.f, acc[i][j][r], ecr[j]);
                                const int ci = gc0 + wc * 64 + j * 16 + md;
                                if (s < rbv[i][r]) { rbv[i][r] = s; rbi[i][r] = ci; }
                            }
#pragma unroll
                    for (int j = 0; j < 4; ++j)
                        ecr[j] = enorm[slice * 4096 + ct * 128 + wc * 64 + j * 16 + md];
#pragma unroll
                    for (int i = 0; i < 4; ++i)
#pragma unroll
                        for (int j = 0; j < 4; ++j) acc[i][j] = (f32x4)0.f;
                }
            }
        }
    }

    // ---- drain: MFMA(255) from set 1 (kt=7), merge ct=31 ------------------
    {
#pragma unroll
        for (int i = 0; i < 4; ++i)
#pragma unroll
            for (int j = 0; j < 4; ++j) {
                acc[i][j] = __builtin_amdgcn_mfma_f32_16x16x32_bf16(fahi[1][i], fbh[1][j], acc[i][j], 0, 0, 0);
                acc[i][j] = __builtin_amdgcn_mfma_f32_16x16x32_bf16(fahi[1][i], fbl[1][j], acc[i][j], 0, 0, 0);
                acc[i][j] = __builtin_amdgcn_mfma_f32_16x16x32_bf16(falo[7][i], fbh[1][j], acc[i][j], 0, 0, 0);
            }
        const int gc0 = slice * 4096 + (CT_PER - 1) * 128;
#pragma unroll
        for (int i = 0; i < 4; ++i)
#pragma unroll
            for (int r = 0; r < 4; ++r)
#pragma unroll
                for (int j = 0; j < 4; ++j) {
                    const float s = fmaf(-2.f, acc[i][j][r], ecr[j]);
                    const int ci = gc0 + wc * 64 + j * 16 + md;
                    if (s < rbv[i][r]) { rbv[i][r] = s; rbi[i][r] = ci; }
                }
    }

    // Epilogue (once per block): reduce across md lanes, atomicMin global key.
#pragma unroll
    for (int i = 0; i < 4; ++i)
#pragma unroll
        for (int r = 0; r < 4; ++r) {
            float bv = rbv[i][r];
            int bi = rbi[i][r];
#pragma unroll
            for (int m = 1; m < 16; m <<= 1) {
                const float ov = __shfl_xor(bv, m, 64);
                const int oi = __shfl_xor(bi, m, 64);
                if (ov < bv || (ov == bv && oi < bi)) { bv = ov; bi = oi; }
            }
            if (md == 0) {
                unsigned int u = __float_as_uint(bv);
                u = (u & 0x80000000u) ? ~u : (u | 0x80000000u);
                const unsigned long long key = ((unsigned long long)u << 32) | (unsigned int)bi;
                atomicMin(&keys[n0 + wr * 64 + i * 16 + quad * 4 + r], key);
            }
        }
}

// ---------------------------------------------------------------------------
// quantized_st + loss partials + integer code counts
__global__ __launch_bounds__(256) void quant_loss_kernel(const float* __restrict__ x,
                                                         const float* __restrict__ emb,
                                                         const unsigned long long* __restrict__ keys,
                                                         float* __restrict__ out,
                                                         float* __restrict__ partials,
                                                         int* __restrict__ icounts) {
    const int blk = blockIdx.x;
    const int b = blk >> 4;
    const int hw0 = (blk & 15) << 6;
    const int l = threadIdx.x & 63;
    const int cq = threadIdx.x >> 6;
    const int hw = hw0 + l;
    const int n = (b << 10) + hw;
    const int code = (int)(keys[n] & 0xFFFFFFFFull);
    if (threadIdx.x < 64) atomicAdd(&icounts[code], 1);
    const float* erow = emb + (size_t)code * D;
    const float* xb = x + (((size_t)b * 256) << 10) + hw;
    float* ob = out + O_QST + (((size_t)b * 256) << 10) + hw;
    float lsum = 0.f;
#pragma unroll 4
    for (int c = cq; c < D; c += 4) {
        const float xv = xb[(size_t)c << 10];
        const float ev = erow[c];
        ob[(size_t)c << 10] = xv + (ev - xv);
        const float d = xv - ev;
        lsum = fmaf(d, d, lsum);
    }
    __shared__ float sm[4];
    const int lane = threadIdx.x & 63, wv = threadIdx.x >> 6;
#pragma unroll
    for (int off = 32; off; off >>= 1) lsum += __shfl_down(lsum, off, 64);
    if (lane == 0) sm[wv] = lsum;
    __syncthreads();
    if (threadIdx.x == 0) partials[blockIdx.x] = sm[0] + sm[1] + sm[2] + sm[3];
}

// ---------------------------------------------------------------------------
// Exclusive scan of icounts -> basearr; also final loss + perplexity scalars.
__global__ __launch_bounds__(256) void scan_final_kernel(const int* __restrict__ icounts,
                                                         int* __restrict__ basearr,
                                                         const float* __restrict__ partials,
                                                         float* __restrict__ out) {
    const int t = threadIdx.x, lane = t & 63, w = t >> 6;
    int loc = 0;
    float ps = 0.f;
    for (int i = 0; i < 32; ++i) {
        const int c = icounts[t * 32 + i];
        loc += c;
        const float p = (float)c * (1.0f / 16384.0f);
        ps += p * logf(p + 1e-10f);
    }
    // inclusive scan of loc within wave
    int v = loc;
#pragma unroll
    for (int off = 1; off < 64; off <<= 1) {
        const int u = __shfl_up(v, off, 64);
        if (lane >= off) v += u;
    }
    __shared__ int wsum[4];
    __shared__ float fs[8];
    if (lane == 63) wsum[w] = v;
    // reduce loss + perplexity partials
    float lp = partials[t];
#pragma unroll
    for (int off = 32; off; off >>= 1) {
        lp += __shfl_down(lp, off, 64);
        ps += __shfl_down(ps, off, 64);
    }
    if (lane == 0) { fs[w] = lp; fs[4 + w] = ps; }
    __syncthreads();
    int pre = 0;
    for (int i = 0; i < w; ++i) pre += wsum[i];
    int b = pre + v - loc;  // exclusive base for this thread's 32 bins
    for (int i = 0; i < 32; ++i) {
        basearr[t * 32 + i] = b;
        b += icounts[t * 32 + i];
    }
    if (t == 0) {
        out[O_LOSS] = 0.25f * ((fs[0] + fs[1] + fs[2] + fs[3]) / 4194304.0f);
        out[O_PERP] = expf(-(fs[4] + fs[5] + fs[6] + fs[7]));
    }
}

// ---------------------------------------------------------------------------
// Counting-sort slot assignment: rowlist[base[code] + pos] = n
__global__ __launch_bounds__(256) void slot_kernel(const unsigned long long* __restrict__ keys,
                                                   const int* __restrict__ basearr,
                                                   int* __restrict__ cursor,
                                                   int* __restrict__ rowlist) {
    const int n = blockIdx.x * 256 + threadIdx.x;
    const int code = (int)(keys[n] & 0xFFFFFFFFull);
    const int pos = atomicAdd(&cursor[code], 1);
    rowlist[basearr[code] + pos] = n;
}

// ---------------------------------------------------------------------------
// Per-code gather-sum of x rows (replaces atomic scatter) fused with EMA.
__global__ __launch_bounds__(256) void gather_ema_kernel(const u16* __restrict__ xhi,
                                                         const u16* __restrict__ xlo,
                                                         const int* __restrict__ icounts,
                                                         const int* __restrict__ basearr,
                                                         const int* __restrict__ rowlist,
                                                         const float* __restrict__ embed_avg,
                                                         const float* __restrict__ cluster_size,
                                                         float* __restrict__ out) {
    const int k = blockIdx.x, c = threadIdx.x;
    const int cnt = icounts[k], b0 = basearr[k];
    float s = 0.f;
    for (int t = 0; t < cnt; ++t) {
        const int n = rowlist[b0 + t];  // wave-uniform
        s += bf2f(xhi[(size_t)n * D + c]) + bf2f(xlo[(size_t)n * D + c]);
    }
    const float ncs = cluster_size[k] * 0.99f + 0.01f * (float)cnt;
    const size_t i = (size_t)k * D + c;
    const float na = embed_avg[i] * 0.99f + 0.01f * s;
    out[O_EAVG + i] = na;
    out[O_EMB + i] = na / fmaxf(ncs, 1e-5f);
    if (c == 0) out[O_CS + k] = ncs;
}

// ---------------------------------------------------------------------------
extern "C" void kernel_launch(void* const* d_in, const int* in_sizes, int n_in,
                              void* d_out, int out_size, void* d_ws, size_t ws_size,
                              hipStream_t stream) {
    const float* x            = (const float*)d_in[0];
    const float* emb          = (const float*)d_in[1];
    const float* cluster_size = (const float*)d_in[2];
    const float* embed_avg    = (const float*)d_in[3];
    float* out = (float*)d_out;
    char* ws = (char*)d_ws;

    float* enorm = (float*)(ws + WS_ENORM);
    unsigned long long* keys = (unsigned long long*)(ws + WS_KEYS);
    int* icounts = (int*)(ws + WS_ICOUNTS);
    int* cursor = (int*)(ws + WS_CURSOR);
    int* basearr = (int*)(ws + WS_BASE);
    int* rowlist = (int*)(ws + WS_ROWLIST);
    float* partials = (float*)(ws + WS_PART);
    u16* xhi = (u16*)(ws + WS_XHI);
    u16* xlo = (u16*)(ws + WS_XLO);
    u16* ehi = (u16*)(ws + WS_EHI);
    u16* elo = (u16*)(ws + WS_ELO);

    static int lds_attr_set = 0;
    if (!lds_attr_set) {
        hipFuncSetAttribute((const void*)dist_kernel,
                            hipFuncAttributeMaxDynamicSharedMemorySize, 131072);
        lds_attr_set = 1;
    }

    prep_kernel<<<9280, 256, 0, stream>>>(emb, x, ehi, elo, enorm, xhi, xlo,
                                          keys, icounts, cursor);
    dist_kernel<<<dim3(SLICES, NROWS / BM), 256, 131072, stream>>>(xhi, xlo, ehi, elo, enorm, keys);
    quant_loss_kernel<<<256, 256, 0, stream>>>(x, emb, keys, out, partials, icounts);
    scan_final_kernel<<<1, 256, 0, stream>>>(icounts, basearr, partials, out);
    slot_kernel<<<NROWS / 256, 256, 0, stream>>>(keys, basearr, cursor, rowlist);
    gather_ema_kernel<<<K_CODES, 256, 0, stream>>>(xhi, xlo, icounts, basearr, rowlist,
                                                   embed_avg, cluster_size, out);
}